// Round 12
// baseline (228.421 us; speedup 1.0000x reference)
//
#include <hip/hip_runtime.h>

#define CDIM 64
#define KCODES 1024
#define ZQ_ELEMS (32 * 64 * 64 * 64)  // 8388608
#define NROWS 131072
#define FLT_BIG 3.402823466e38f
#define RPB 128                       // rows per block
#define NBLK (NROWS / RPB)            // 1024
#define CSTRIDE 49                    // sKey row stride (floats); 48 slots used
#define DELTA 1e-4f                   // screening slack (capture bound ~4.8e-5)

// ws layout: [0,8KB) part | [16KB,20KB) Bsq | [32KB,+128KB) e1 | then e2
#define WS_BSQ_OFF 16384
#define WS_E1_OFF  32768
#define WS_E2_OFF  (32768 + 131072)

typedef __bf16 bf16x8 __attribute__((ext_vector_type(8)));
typedef float  f32x4  __attribute__((ext_vector_type(4)));

// numpy-exact pairwise sum of squares (8 accumulators, numpy pairwise order)
__device__ __forceinline__ float pairwise_sq64(const float* v) {
    float r[8];
    #pragma unroll
    for (int j = 0; j < 8; ++j) r[j] = __fmul_rn(v[j], v[j]);
    #pragma unroll
    for (int m = 1; m < 8; ++m) {
        #pragma unroll
        for (int j = 0; j < 8; ++j)
            r[j] = __fadd_rn(r[j], __fmul_rn(v[8 * m + j], v[8 * m + j]));
    }
    return __fadd_rn(__fadd_rn(__fadd_rn(r[0], r[1]), __fadd_rn(r[2], r[3])),
                     __fadd_rn(__fadd_rn(r[4], r[5]), __fadd_rn(r[6], r[7])));
}

// ---------------- prep: exact code norms + bf16-split codebook, B-fragment layout ----
__global__ __launch_bounds__(256) void vq_prep(const float* __restrict__ cb,
                                               float* __restrict__ Bsq,
                                               __bf16* __restrict__ e1,
                                               __bf16* __restrict__ e2) {
    const int k = blockIdx.x * 256 + threadIdx.x;   // 4 blocks -> 1024 codes
    const float* __restrict__ ck = cb + k * CDIM;
    float v[CDIM];
    #pragma unroll
    for (int q = 0; q < 16; ++q) {
        float4 t = ((const float4*)ck)[q];
        v[4 * q + 0] = t.x; v[4 * q + 1] = t.y; v[4 * q + 2] = t.z; v[4 * q + 3] = t.w;
    }
    Bsq[k] = pairwise_sq64(v);

    __bf16 h[CDIM], l[CDIM];
    #pragma unroll
    for (int c = 0; c < CDIM; ++c) {
        h[c] = (__bf16)v[c];
        l[c] = (__bf16)(v[c] - (float)h[c]);
    }
    const int t = k >> 4, kin = k & 15;
    bf16x8* F1 = (bf16x8*)e1;
    bf16x8* F2 = (bf16x8*)e2;
    #pragma unroll
    for (int ks = 0; ks < 2; ++ks) {
        #pragma unroll
        for (int g = 0; g < 4; ++g) {
            bf16x8 a, b;
            #pragma unroll
            for (int i = 0; i < 8; ++i) {
                a[i] = h[ks * 32 + 8 * g + i];
                b[i] = l[ks * 32 + 8 * g + i];
            }
            const int off = (t * 2 + ks) * 64 + ((g << 4) | kin);
            F1[off] = a;
            F2[off] = b;
        }
    }
}

// branchless sorted-3 insert: fmaf + pack(and_or) + min + 2*med3
#define INS(s, j, accv, Bv, code0) \
    { \
        const float vv = __fmaf_rn(-2.f, (accv), (Bv)); \
        const float kk = __int_as_float((__float_as_int(vv) & 0xFFFFFC00) | (code0)); \
        const float o0 = K0[s][j], o1 = K1[s][j], o2 = K2[s][j]; \
        K0[s][j] = fminf(o0, kk); \
        K1[s][j] = __builtin_amdgcn_fmed3f(o0, o1, kk); \
        K2[s][j] = __builtin_amdgcn_fmed3f(o1, o2, kk); \
    }

// ---------------- main: MFMA screen (LDS-staged fragments) + exact rescue ----
__global__ __launch_bounds__(256, 4) void vq_main(const float* __restrict__ z,
                                                  const float* __restrict__ cb,
                                                  const float* __restrict__ Bsq,
                                                  const __bf16* __restrict__ e1,
                                                  const __bf16* __restrict__ e2,
                                                  float* __restrict__ zq_out,
                                                  float* __restrict__ idx_out,
                                                  double* __restrict__ part) {
    // union: [phase 0/1] 32 frag-planes x 65 slots x 16B = 33280 B
    //        [phase 2]   sKey: 128 x 49 floats = 25088 B; reduce arrays at +25088
    __shared__ __align__(16) unsigned char sU[32 * 65 * 16];
    __shared__ float  sB[KCODES];
    __shared__ double sP2[2];

    const int tid = threadIdx.x;
    const int n0 = blockIdx.x * RPB;
    const int b = n0 >> 12;
    const int hw0 = n0 & 4095;
    const float* __restrict__ zb = z + ((size_t)b << 18) + hw0;

    for (int k = tid; k < KCODES; k += 256) sB[k] = Bsq[k];

    // ---- phase 0: cooperative z staging into bf16 hi/lo fragment planes ----
    {
        bf16x8* __restrict__ zfw = (bf16x8*)sU;
        const int r = tid & 127;             // row
        const int h = tid >> 7;              // Q half
        const int w = r >> 5, s = (r >> 4) & 1, li = r & 15;
        #pragma unroll
        for (int g = 0; g < 4; ++g) {
            bf16x8 hi, lo;
            #pragma unroll
            for (int i = 0; i < 8; ++i) {
                const float fv = zb[((size_t)(32 * h + 8 * g + i) << 12) + r];
                const __bf16 hv = (__bf16)fv;
                hi[i] = hv;
                lo[i] = (__bf16)(fv - (float)hv);
            }
            const int slot = (g << 4) | li;
            zfw[(w * 8 + s * 2 + h) * 65 + slot] = hi;         // H=0
            zfw[(w * 8 + 4 + s * 2 + h) * 65 + slot] = lo;     // H=1
        }
    }
    __syncthreads();

    // ---- phase 1: MFMA screen; wave w owns rows [32w,32w+32) x all 1024 codes ----
    const int lane = tid & 63, w = tid >> 6;
    const int g = lane >> 4, li = lane & 15;

    const bf16x8* __restrict__ zf = (const bf16x8*)sU;
    const bf16x8 zh00 = zf[(w * 8 + 0) * 65 + lane];
    const bf16x8 zh01 = zf[(w * 8 + 1) * 65 + lane];
    const bf16x8 zh10 = zf[(w * 8 + 2) * 65 + lane];
    const bf16x8 zh11 = zf[(w * 8 + 3) * 65 + lane];
    const bf16x8 zl00 = zf[(w * 8 + 4) * 65 + lane];
    const bf16x8 zl01 = zf[(w * 8 + 5) * 65 + lane];
    const bf16x8 zl10 = zf[(w * 8 + 6) * 65 + lane];
    const bf16x8 zl11 = zf[(w * 8 + 7) * 65 + lane];

    float K0[2][4], K1[2][4], K2[2][4];
    #pragma unroll
    for (int s = 0; s < 2; ++s)
        #pragma unroll
        for (int j = 0; j < 4; ++j) { K0[s][j] = FLT_BIG; K1[s][j] = FLT_BIG; K2[s][j] = FLT_BIG; }

    const bf16x8* __restrict__ pe1 = (const bf16x8*)e1 + lane;
    const bf16x8* __restrict__ pe2 = (const bf16x8*)e2 + lane;
    const f32x4 zero = {0.f, 0.f, 0.f, 0.f};
    int tbli = li;

    // software-pipelined: current regs c*, prefetch next before compute
    bf16x8 c1a = pe1[0], c1b = pe1[64], c2a = pe2[0], c2b = pe2[64];
    float cB = sB[tbli];

    #pragma unroll 4
    for (int t = 0; t < 64; ++t) {
        const bf16x8 e1a = c1a, e1b = c1b, e2a = c2a, e2b = c2b;
        const float Bv = cB;
        const int code0 = tbli;
        pe1 += 128; pe2 += 128; tbli += 16;
        if (t < 63) {                      // wave-uniform branch, cheap
            c1a = pe1[0]; c1b = pe1[64];
            c2a = pe2[0]; c2b = pe2[64];
            cB = sB[tbli];
        }

        __builtin_amdgcn_s_setprio(1);
        f32x4 aA0 = __builtin_amdgcn_mfma_f32_16x16x32_bf16(zh00, e1a, zero, 0, 0, 0);
        aA0       = __builtin_amdgcn_mfma_f32_16x16x32_bf16(zh01, e1b, aA0, 0, 0, 0);
        f32x4 aB0 = __builtin_amdgcn_mfma_f32_16x16x32_bf16(zh00, e2a, zero, 0, 0, 0);
        aB0       = __builtin_amdgcn_mfma_f32_16x16x32_bf16(zh01, e2b, aB0, 0, 0, 0);
        aB0       = __builtin_amdgcn_mfma_f32_16x16x32_bf16(zl00, e1a, aB0, 0, 0, 0);
        aB0       = __builtin_amdgcn_mfma_f32_16x16x32_bf16(zl01, e1b, aB0, 0, 0, 0);
        f32x4 aA1 = __builtin_amdgcn_mfma_f32_16x16x32_bf16(zh10, e1a, zero, 0, 0, 0);
        aA1       = __builtin_amdgcn_mfma_f32_16x16x32_bf16(zh11, e1b, aA1, 0, 0, 0);
        f32x4 aB1 = __builtin_amdgcn_mfma_f32_16x16x32_bf16(zh10, e2a, zero, 0, 0, 0);
        aB1       = __builtin_amdgcn_mfma_f32_16x16x32_bf16(zh11, e2b, aB1, 0, 0, 0);
        aB1       = __builtin_amdgcn_mfma_f32_16x16x32_bf16(zl10, e1a, aB1, 0, 0, 0);
        aB1       = __builtin_amdgcn_mfma_f32_16x16x32_bf16(zl11, e1b, aB1, 0, 0, 0);
        __builtin_amdgcn_s_setprio(0);

        #pragma unroll
        for (int j = 0; j < 4; ++j) INS(0, j, aA0[j] + aB0[j], Bv, code0)
        #pragma unroll
        for (int j = 0; j < 4; ++j) INS(1, j, aA1[j] + aB1[j], Bv, code0)
    }

    __syncthreads();   // frag planes dead; reuse sU as sKey + reduce arrays

    float* __restrict__ sKey = (float*)sU;
    float* __restrict__ sRd = (float*)(sU + 25088);
    int*   __restrict__ sRk = (int*)(sU + 25088 + 512);
    #pragma unroll
    for (int s = 0; s < 2; ++s) {
        #pragma unroll
        for (int j = 0; j < 4; ++j) {
            const int row = 32 * w + 16 * s + 4 * g + j;
            const int base = row * CSTRIDE + li * 3;
            sKey[base + 0] = K0[s][j];
            sKey[base + 1] = K1[s][j];
            sKey[base + 2] = K2[s][j];
        }
    }
    __syncthreads();

    // ---- phase 2: exact numpy-semantics rescue; 256 threads (2 halves per row) ----
    {
        const int r = tid & 127;
        const int half = tid >> 7;
        const int n = n0 + r;

        float gmin = FLT_BIG;
        #pragma unroll
        for (int s2 = 0; s2 < 48; ++s2) gmin = fminf(gmin, sKey[r * CSTRIDE + s2]);
        const float thr = gmin + DELTA;

        float zrow[CDIM];
        const float* __restrict__ zp = zb + r;
        #pragma unroll
        for (int c = 0; c < CDIM; ++c) zrow[c] = zp[(size_t)c << 12];  // coalesced
        const float A = pairwise_sq64(zrow);

        float bd = FLT_BIG;
        int bk = 1 << 30;
        const int sbeg = half * 24;
        for (int s2 = sbeg; s2 < sbeg + 24; ++s2) {
            const float kv = sKey[r * CSTRIDE + s2];
            if (kv <= thr) {
                const int k = __float_as_int(kv) & 0x3FF;
                const float4* __restrict__ ek = (const float4*)(cb + (size_t)k * CDIM);
                float m = 0.f;
                #pragma unroll
                for (int q = 0; q < 16; ++q) {      // BLAS order: sequential in c
                    float4 e = ek[q];
                    m = __fmaf_rn(zrow[4 * q + 0], e.x, m);
                    m = __fmaf_rn(zrow[4 * q + 1], e.y, m);
                    m = __fmaf_rn(zrow[4 * q + 2], e.z, m);
                    m = __fmaf_rn(zrow[4 * q + 3], e.w, m);
                }
                const float d = __fsub_rn(__fadd_rn(A, sB[k]), __fadd_rn(m, m));
                if (d < bd || (d == bd && k < bk)) { bd = d; bk = k; }
            }
        }

        if (half == 1) { sRd[r] = bd; sRk[r] = bk; }
        __syncthreads();

        if (tid < RPB) {
            const float d1 = sRd[r];
            const int   k1 = sRk[r];
            if (d1 < bd || (d1 == bd && k1 < bk)) { bd = d1; bk = k1; }  // lex-min combine

            idx_out[n] = (float)bk;

            const float4* __restrict__ cq = (const float4*)(cb + (size_t)bk * CDIM);
            float* __restrict__ zo = zq_out + ((size_t)b << 18) + hw0 + r;
            float lsum = 0.f;
            #pragma unroll
            for (int q = 0; q < 16; ++q) {
                float4 qv = cq[q];
                zo[(size_t)(4 * q + 0) << 12] = qv.x;
                zo[(size_t)(4 * q + 1) << 12] = qv.y;
                zo[(size_t)(4 * q + 2) << 12] = qv.z;
                zo[(size_t)(4 * q + 3) << 12] = qv.w;
                lsum = fmaf(qv.x - zrow[4 * q + 0], qv.x - zrow[4 * q + 0], lsum);
                lsum = fmaf(qv.y - zrow[4 * q + 1], qv.y - zrow[4 * q + 1], lsum);
                lsum = fmaf(qv.z - zrow[4 * q + 2], qv.z - zrow[4 * q + 2], lsum);
                lsum = fmaf(qv.w - zrow[4 * q + 3], qv.w - zrow[4 * q + 3], lsum);
            }

            double ls = (double)lsum;
            for (int off = 32; off > 0; off >>= 1) ls += __shfl_down(ls, off, 64);
            if ((tid & 63) == 0) sP2[tid >> 6] = ls;
        }
    }
    __syncthreads();
    if (tid == 0) part[blockIdx.x] = sP2[0] + sP2[1];
}

__global__ void vq_finalize(const double* __restrict__ part, float* __restrict__ loss_out) {
    __shared__ double s[16];
    const int tid = threadIdx.x;       // 1024 threads, one block
    double v = part[tid];
    for (int off = 32; off > 0; off >>= 1) v += __shfl_down(v, off, 64);
    if ((tid & 63) == 0) s[tid >> 6] = v;
    __syncthreads();
    if (tid == 0) {
        double t = 0.0;
        #pragma unroll
        for (int i = 0; i < 16; ++i) t += s[i];
        // loss = codebook_loss + 0.25*commitment = 1.25 * mean((z_q - z)^2)
        *loss_out = (float)(1.25 * t / (double)ZQ_ELEMS);
    }
}

extern "C" void kernel_launch(void* const* d_in, const int* in_sizes, int n_in,
                              void* d_out, int out_size, void* d_ws, size_t ws_size,
                              hipStream_t stream) {
    const float* z  = (const float*)d_in[0];
    const float* cb = (const float*)d_in[1];
    float* out  = (float*)d_out;
    float* zq   = out;                       // 8388608
    float* loss = out + ZQ_ELEMS;            // 1
    float* idx  = out + ZQ_ELEMS + 1;        // 131072
    char* ws = (char*)d_ws;
    double* part = (double*)ws;              // 1024 doubles
    float* Bsq   = (float*)(ws + WS_BSQ_OFF);
    __bf16* e1   = (__bf16*)(ws + WS_E1_OFF);
    __bf16* e2   = (__bf16*)(ws + WS_E2_OFF);

    vq_prep<<<4, 256, 0, stream>>>(cb, Bsq, e1, e2);
    vq_main<<<NBLK, 256, 0, stream>>>(z, cb, Bsq, e1, e2, zq, idx, part);
    vq_finalize<<<1, 1024, 0, stream>>>(part, loss);
}

// Round 13
// 90.562 us; speedup vs baseline: 2.5223x; 2.5223x over previous
//
#include <hip/hip_runtime.h>

#define CDIM 64
#define KCODES 1024
#define ZQ_ELEMS (32 * 64 * 64 * 64)  // 8388608
#define NROWS 131072
#define FLT_BIG 3.402823466e38f
#define RPB 128                       // rows per block
#define NBLK (NROWS / RPB)            // 1024
#define CSTRIDE 49                    // sKey row stride (floats); 48 slots used
#define DELTA 5e-4f                   // screening slack (z_lo dropped; ~50-sigma margin)

// ws layout: [0,8KB) part | [16KB,20KB) Bsq | [32KB,+128KB) e1 | then e2
#define WS_BSQ_OFF 16384
#define WS_E1_OFF  32768
#define WS_E2_OFF  (32768 + 131072)

typedef __bf16 bf16x8 __attribute__((ext_vector_type(8)));
typedef float  f32x4  __attribute__((ext_vector_type(4)));

// numpy-exact pairwise sum of squares (8 accumulators, numpy pairwise order)
__device__ __forceinline__ float pairwise_sq64(const float* v) {
    float r[8];
    #pragma unroll
    for (int j = 0; j < 8; ++j) r[j] = __fmul_rn(v[j], v[j]);
    #pragma unroll
    for (int m = 1; m < 8; ++m) {
        #pragma unroll
        for (int j = 0; j < 8; ++j)
            r[j] = __fadd_rn(r[j], __fmul_rn(v[8 * m + j], v[8 * m + j]));
    }
    return __fadd_rn(__fadd_rn(__fadd_rn(r[0], r[1]), __fadd_rn(r[2], r[3])),
                     __fadd_rn(__fadd_rn(r[4], r[5]), __fadd_rn(r[6], r[7])));
}

// ---------------- prep: exact code norms + bf16-split codebook, B-fragment layout ----
__global__ __launch_bounds__(256) void vq_prep(const float* __restrict__ cb,
                                               float* __restrict__ Bsq,
                                               __bf16* __restrict__ e1,
                                               __bf16* __restrict__ e2) {
    const int k = blockIdx.x * 256 + threadIdx.x;   // 4 blocks -> 1024 codes
    const float* __restrict__ ck = cb + k * CDIM;
    float v[CDIM];
    #pragma unroll
    for (int q = 0; q < 16; ++q) {
        float4 t = ((const float4*)ck)[q];
        v[4 * q + 0] = t.x; v[4 * q + 1] = t.y; v[4 * q + 2] = t.z; v[4 * q + 3] = t.w;
    }
    Bsq[k] = pairwise_sq64(v);

    __bf16 h[CDIM], l[CDIM];
    #pragma unroll
    for (int c = 0; c < CDIM; ++c) {
        h[c] = (__bf16)v[c];
        l[c] = (__bf16)(v[c] - (float)h[c]);
    }
    const int t = k >> 4, kin = k & 15;
    bf16x8* F1 = (bf16x8*)e1;
    bf16x8* F2 = (bf16x8*)e2;
    #pragma unroll
    for (int ks = 0; ks < 2; ++ks) {
        #pragma unroll
        for (int g = 0; g < 4; ++g) {
            bf16x8 a, b;
            #pragma unroll
            for (int i = 0; i < 8; ++i) {
                a[i] = h[ks * 32 + 8 * g + i];
                b[i] = l[ks * 32 + 8 * g + i];
            }
            const int off = (t * 2 + ks) * 64 + ((g << 4) | kin);
            F1[off] = a;
            F2[off] = b;
        }
    }
}

// branchless sorted-3 insert: 1 min + 2 med3
#define INS(s, j, accv) \
    { \
        const float v = __fmaf_rn(-2.f, (accv), Bval); \
        const float kk = __int_as_float((__float_as_int(v) & 0xFFFFFC00) | tbli); \
        const float o0 = K0[s][j], o1 = K1[s][j], o2 = K2[s][j]; \
        K0[s][j] = fminf(o0, kk); \
        K1[s][j] = __builtin_amdgcn_fmed3f(o0, o1, kk); \
        K2[s][j] = __builtin_amdgcn_fmed3f(o1, o2, kk); \
    }

// ---------------- main: MFMA screen (z_hi only; 4 resident frags) + exact rescue ----
__global__ __launch_bounds__(256, 4) void vq_main(const float* __restrict__ z,
                                                  const float* __restrict__ cb,
                                                  const float* __restrict__ Bsq,
                                                  const __bf16* __restrict__ e1,
                                                  const __bf16* __restrict__ e2,
                                                  float* __restrict__ zq_out,
                                                  float* __restrict__ idx_out,
                                                  double* __restrict__ part) {
    // union: [phase 0/1] 16 frag-planes x 65 slots x 16B = 16640 B
    //        [phase 2]   sKey: 128 rows x 49 floats = 25088 B
    __shared__ __align__(16) unsigned char sU[25152];
    __shared__ float  sB[KCODES];
    __shared__ double sP2[2];

    const int tid = threadIdx.x;
    const int n0 = blockIdx.x * RPB;
    const int b = n0 >> 12;
    const int hw0 = n0 & 4095;
    const float* __restrict__ zb = z + ((size_t)b << 18) + hw0;

    for (int k = tid; k < KCODES; k += 256) sB[k] = Bsq[k];

    // ---- phase 0: cooperative z staging into bf16-hi fragment planes ----
    // plane(w,s,h) = w*4 + s*2 + h ; slot = g*16+li ; 65 slots/plane
    {
        bf16x8* __restrict__ zfw = (bf16x8*)sU;
        const int r = tid & 127;             // row
        const int h = tid >> 7;              // K half
        const int w = r >> 5, s = (r >> 4) & 1, li = r & 15;
        #pragma unroll
        for (int g = 0; g < 4; ++g) {
            bf16x8 hi;
            #pragma unroll
            for (int i = 0; i < 8; ++i) {
                const float fv = zb[((size_t)(32 * h + 8 * g + i) << 12) + r];
                hi[i] = (__bf16)fv;
            }
            const int slot = (g << 4) | li;
            zfw[(w * 4 + s * 2 + h) * 65 + slot] = hi;
        }
    }
    __syncthreads();

    // ---- phase 1: MFMA screen; wave w owns rows [32w,32w+32) x all 1024 codes ----
    const int lane = tid & 63, w = tid >> 6;
    const int g = lane >> 4, li = lane & 15;

    const bf16x8* __restrict__ zf = (const bf16x8*)sU;
    const bf16x8 zh00 = zf[(w * 4 + 0) * 65 + lane];
    const bf16x8 zh01 = zf[(w * 4 + 1) * 65 + lane];
    const bf16x8 zh10 = zf[(w * 4 + 2) * 65 + lane];
    const bf16x8 zh11 = zf[(w * 4 + 3) * 65 + lane];

    float K0[2][4], K1[2][4], K2[2][4];
    #pragma unroll
    for (int s = 0; s < 2; ++s)
        #pragma unroll
        for (int j = 0; j < 4; ++j) { K0[s][j] = FLT_BIG; K1[s][j] = FLT_BIG; K2[s][j] = FLT_BIG; }

    const bf16x8* __restrict__ pe1 = (const bf16x8*)e1 + lane;
    const bf16x8* __restrict__ pe2 = (const bf16x8*)e2 + lane;
    const f32x4 zero = {0.f, 0.f, 0.f, 0.f};
    int tbli = li;

    for (int t = 0; t < 64; ++t) {
        const bf16x8 e1a = pe1[0];
        const bf16x8 e1b = pe1[64];
        const bf16x8 e2a = pe2[0];
        const bf16x8 e2b = pe2[64];
        const float Bval = sB[tbli];

        // z_hi * (e1 + e2) = z_hi * e  (z_lo dropped; absorbed by DELTA)
        f32x4 aA0 = __builtin_amdgcn_mfma_f32_16x16x32_bf16(zh00, e1a, zero, 0, 0, 0);
        aA0       = __builtin_amdgcn_mfma_f32_16x16x32_bf16(zh01, e1b, aA0, 0, 0, 0);
        f32x4 aB0 = __builtin_amdgcn_mfma_f32_16x16x32_bf16(zh00, e2a, zero, 0, 0, 0);
        aB0       = __builtin_amdgcn_mfma_f32_16x16x32_bf16(zh01, e2b, aB0, 0, 0, 0);
        f32x4 aA1 = __builtin_amdgcn_mfma_f32_16x16x32_bf16(zh10, e1a, zero, 0, 0, 0);
        aA1       = __builtin_amdgcn_mfma_f32_16x16x32_bf16(zh11, e1b, aA1, 0, 0, 0);
        f32x4 aB1 = __builtin_amdgcn_mfma_f32_16x16x32_bf16(zh10, e2a, zero, 0, 0, 0);
        aB1       = __builtin_amdgcn_mfma_f32_16x16x32_bf16(zh11, e2b, aB1, 0, 0, 0);

        #pragma unroll
        for (int j = 0; j < 4; ++j) INS(0, j, aA0[j] + aB0[j])
        #pragma unroll
        for (int j = 0; j < 4; ++j) INS(1, j, aA1[j] + aB1[j])

        pe1 += 128;
        pe2 += 128;
        tbli += 16;
    }

    __syncthreads();   // frag planes dead; reuse sU as sKey

    float* __restrict__ sKey = (float*)sU;
    #pragma unroll
    for (int s = 0; s < 2; ++s) {
        #pragma unroll
        for (int j = 0; j < 4; ++j) {
            const int row = 32 * w + 16 * s + 4 * g + j;
            const int base = row * CSTRIDE + li * 3;
            sKey[base + 0] = K0[s][j];
            sKey[base + 1] = K1[s][j];
            sKey[base + 2] = K2[s][j];
        }
    }
    __syncthreads();

    // ---- phase 2: exact numpy-semantics rescue, one thread per row ----
    if (tid < RPB) {
        const int r = tid;
        const int n = n0 + r;

        float gmin = FLT_BIG;
        #pragma unroll
        for (int s2 = 0; s2 < 48; ++s2) gmin = fminf(gmin, sKey[r * CSTRIDE + s2]);
        const float thr = gmin + DELTA;

        float zrow[CDIM];
        const float* __restrict__ zp = zb + r;
        #pragma unroll
        for (int c = 0; c < CDIM; ++c) zrow[c] = zp[(size_t)c << 12];  // coalesced
        const float A = pairwise_sq64(zrow);

        float bd = FLT_BIG;
        int bk = 1 << 30;
        for (int s2 = 0; s2 < 48; ++s2) {
            const float kv = sKey[r * CSTRIDE + s2];
            if (kv <= thr) {
                const int k = __float_as_int(kv) & 0x3FF;
                const float4* __restrict__ ek = (const float4*)(cb + (size_t)k * CDIM);
                float m = 0.f;
                #pragma unroll
                for (int q = 0; q < 16; ++q) {      // BLAS order: sequential in c
                    float4 e = ek[q];
                    m = __fmaf_rn(zrow[4 * q + 0], e.x, m);
                    m = __fmaf_rn(zrow[4 * q + 1], e.y, m);
                    m = __fmaf_rn(zrow[4 * q + 2], e.z, m);
                    m = __fmaf_rn(zrow[4 * q + 3], e.w, m);
                }
                const float d = __fsub_rn(__fadd_rn(A, sB[k]), __fadd_rn(m, m));
                if (d < bd || (d == bd && k < bk)) { bd = d; bk = k; }
            }
        }

        idx_out[n] = (float)bk;

        const float4* __restrict__ cq = (const float4*)(cb + (size_t)bk * CDIM);
        float* __restrict__ zo = zq_out + ((size_t)b << 18) + hw0 + r;
        float lsum = 0.f;
        #pragma unroll
        for (int q = 0; q < 16; ++q) {
            float4 qv = cq[q];
            zo[(size_t)(4 * q + 0) << 12] = qv.x;
            zo[(size_t)(4 * q + 1) << 12] = qv.y;
            zo[(size_t)(4 * q + 2) << 12] = qv.z;
            zo[(size_t)(4 * q + 3) << 12] = qv.w;
            lsum = fmaf(qv.x - zrow[4 * q + 0], qv.x - zrow[4 * q + 0], lsum);
            lsum = fmaf(qv.y - zrow[4 * q + 1], qv.y - zrow[4 * q + 1], lsum);
            lsum = fmaf(qv.z - zrow[4 * q + 2], qv.z - zrow[4 * q + 2], lsum);
            lsum = fmaf(qv.w - zrow[4 * q + 3], qv.w - zrow[4 * q + 3], lsum);
        }

        double ls = (double)lsum;
        for (int off = 32; off > 0; off >>= 1) ls += __shfl_down(ls, off, 64);
        if ((tid & 63) == 0) sP2[tid >> 6] = ls;
    }
    __syncthreads();
    if (tid == 0) part[blockIdx.x] = sP2[0] + sP2[1];
}

__global__ void vq_finalize(const double* __restrict__ part, float* __restrict__ loss_out) {
    __shared__ double s[16];
    const int tid = threadIdx.x;       // 1024 threads, one block
    double v = part[tid];
    for (int off = 32; off > 0; off >>= 1) v += __shfl_down(v, off, 64);
    if ((tid & 63) == 0) s[tid >> 6] = v;
    __syncthreads();
    if (tid == 0) {
        double t = 0.0;
        #pragma unroll
        for (int i = 0; i < 16; ++i) t += s[i];
        // loss = codebook_loss + 0.25*commitment = 1.25 * mean((z_q - z)^2)
        *loss_out = (float)(1.25 * t / (double)ZQ_ELEMS);
    }
}

extern "C" void kernel_launch(void* const* d_in, const int* in_sizes, int n_in,
                              void* d_out, int out_size, void* d_ws, size_t ws_size,
                              hipStream_t stream) {
    const float* z  = (const float*)d_in[0];
    const float* cb = (const float*)d_in[1];
    float* out  = (float*)d_out;
    float* zq   = out;                       // 8388608
    float* loss = out + ZQ_ELEMS;            // 1
    float* idx  = out + ZQ_ELEMS + 1;        // 131072
    char* ws = (char*)d_ws;
    double* part = (double*)ws;              // 1024 doubles
    float* Bsq   = (float*)(ws + WS_BSQ_OFF);
    __bf16* e1   = (__bf16*)(ws + WS_E1_OFF);
    __bf16* e2   = (__bf16*)(ws + WS_E2_OFF);

    vq_prep<<<4, 256, 0, stream>>>(cb, Bsq, e1, e2);
    vq_main<<<NBLK, 256, 0, stream>>>(z, cb, Bsq, e1, e2, zq, idx, part);
    vq_finalize<<<1, 1024, 0, stream>>>(part, loss);
}

// Round 14
// 90.219 us; speedup vs baseline: 2.5319x; 1.0038x over previous
//
#include <hip/hip_runtime.h>

#define CDIM 64
#define KCODES 1024
#define ZQ_ELEMS (32 * 64 * 64 * 64)  // 8388608
#define NROWS 131072
#define FLT_BIG 3.402823466e38f
#define RPB 128                       // rows per block
#define NBLK (NROWS / RPB)            // 1024
#define CSTRIDE 49                    // sKey row stride (floats); 48 slots used
#define DELTA 5e-4f                   // screening slack (z_lo dropped; ~50-sigma margin)

// ws layout: [0,8KB) part | [16KB,20KB) Bsq | [32KB,+128KB) e1 | then e2 (+2KB overread pad)
#define WS_BSQ_OFF 16384
#define WS_E1_OFF  32768
#define WS_E2_OFF  (32768 + 131072)

typedef __bf16 bf16x8 __attribute__((ext_vector_type(8)));
typedef float  f32x4  __attribute__((ext_vector_type(4)));

// numpy-exact pairwise sum of squares (8 accumulators, numpy pairwise order)
__device__ __forceinline__ float pairwise_sq64(const float* v) {
    float r[8];
    #pragma unroll
    for (int j = 0; j < 8; ++j) r[j] = __fmul_rn(v[j], v[j]);
    #pragma unroll
    for (int m = 1; m < 8; ++m) {
        #pragma unroll
        for (int j = 0; j < 8; ++j)
            r[j] = __fadd_rn(r[j], __fmul_rn(v[8 * m + j], v[8 * m + j]));
    }
    return __fadd_rn(__fadd_rn(__fadd_rn(r[0], r[1]), __fadd_rn(r[2], r[3])),
                     __fadd_rn(__fadd_rn(r[4], r[5]), __fadd_rn(r[6], r[7])));
}

// ---------------- prep: exact code norms + bf16-split codebook, B-fragment layout ----
__global__ __launch_bounds__(256) void vq_prep(const float* __restrict__ cb,
                                               float* __restrict__ Bsq,
                                               __bf16* __restrict__ e1,
                                               __bf16* __restrict__ e2) {
    const int k = blockIdx.x * 256 + threadIdx.x;   // 4 blocks -> 1024 codes
    const float* __restrict__ ck = cb + k * CDIM;
    float v[CDIM];
    #pragma unroll
    for (int q = 0; q < 16; ++q) {
        float4 t = ((const float4*)ck)[q];
        v[4 * q + 0] = t.x; v[4 * q + 1] = t.y; v[4 * q + 2] = t.z; v[4 * q + 3] = t.w;
    }
    Bsq[k] = pairwise_sq64(v);

    __bf16 h[CDIM], l[CDIM];
    #pragma unroll
    for (int c = 0; c < CDIM; ++c) {
        h[c] = (__bf16)v[c];
        l[c] = (__bf16)(v[c] - (float)h[c]);
    }
    const int t = k >> 4, kin = k & 15;
    bf16x8* F1 = (bf16x8*)e1;
    bf16x8* F2 = (bf16x8*)e2;
    #pragma unroll
    for (int ks = 0; ks < 2; ++ks) {
        #pragma unroll
        for (int g = 0; g < 4; ++g) {
            bf16x8 a, b;
            #pragma unroll
            for (int i = 0; i < 8; ++i) {
                a[i] = h[ks * 32 + 8 * g + i];
                b[i] = l[ks * 32 + 8 * g + i];
            }
            const int off = (t * 2 + ks) * 64 + ((g << 4) | kin);
            F1[off] = a;
            F2[off] = b;
        }
    }
}

// branchless sorted-3 insert: fmaf + and_or pack + min + 2*med3
#define INS(s, j, accv, Bv, code0) \
    { \
        const float vv = __fmaf_rn(-2.f, (accv), (Bv)); \
        const float kk = __int_as_float((__float_as_int(vv) & 0xFFFFFC00) | (code0)); \
        const float o0 = K0[s][j], o1 = K1[s][j], o2 = K2[s][j]; \
        K0[s][j] = fminf(o0, kk); \
        K1[s][j] = __builtin_amdgcn_fmed3f(o0, o1, kk); \
        K2[s][j] = __builtin_amdgcn_fmed3f(o1, o2, kk); \
    }

// one sub-iteration: chained 4-MFMA per row-set, then 8 inserts
#define TILE_COMPUTE(E1a, E1b, E2a, E2b, code0) \
    { \
        const float Bv = sB[code0]; \
        f32x4 a0 = __builtin_amdgcn_mfma_f32_16x16x32_bf16(zh00, E1a, zero, 0, 0, 0); \
        a0       = __builtin_amdgcn_mfma_f32_16x16x32_bf16(zh01, E1b, a0, 0, 0, 0); \
        a0       = __builtin_amdgcn_mfma_f32_16x16x32_bf16(zh00, E2a, a0, 0, 0, 0); \
        a0       = __builtin_amdgcn_mfma_f32_16x16x32_bf16(zh01, E2b, a0, 0, 0, 0); \
        f32x4 a1 = __builtin_amdgcn_mfma_f32_16x16x32_bf16(zh10, E1a, zero, 0, 0, 0); \
        a1       = __builtin_amdgcn_mfma_f32_16x16x32_bf16(zh11, E1b, a1, 0, 0, 0); \
        a1       = __builtin_amdgcn_mfma_f32_16x16x32_bf16(zh10, E2a, a1, 0, 0, 0); \
        a1       = __builtin_amdgcn_mfma_f32_16x16x32_bf16(zh11, E2b, a1, 0, 0, 0); \
        INS(0, 0, a0[0], Bv, code0) INS(0, 1, a0[1], Bv, code0) \
        INS(0, 2, a0[2], Bv, code0) INS(0, 3, a0[3], Bv, code0) \
        INS(1, 0, a1[0], Bv, code0) INS(1, 1, a1[1], Bv, code0) \
        INS(1, 2, a1[2], Bv, code0) INS(1, 3, a1[3], Bv, code0) \
    }

// ---------------- main: MFMA screen (reg-dbuf e-stream) + exact rescue ----------------
__global__ __launch_bounds__(256, 4) void vq_main(const float* __restrict__ z,
                                                  const float* __restrict__ cb,
                                                  const float* __restrict__ Bsq,
                                                  const __bf16* __restrict__ e1,
                                                  const __bf16* __restrict__ e2,
                                                  float* __restrict__ zq_out,
                                                  float* __restrict__ idx_out,
                                                  double* __restrict__ part) {
    // union: [phase 0/1] 16 frag-planes x 65 slots x 16B = 16640 B
    //        [phase 2]   sKey: 128 rows x 49 floats = 25088 B
    __shared__ __align__(16) unsigned char sU[25152];
    __shared__ float  sB[KCODES];
    __shared__ double sP2[2];

    const int tid = threadIdx.x;
    const int n0 = blockIdx.x * RPB;
    const int b = n0 >> 12;
    const int hw0 = n0 & 4095;
    const float* __restrict__ zb = z + ((size_t)b << 18) + hw0;

    for (int k = tid; k < KCODES; k += 256) sB[k] = Bsq[k];

    // ---- phase 0: cooperative z staging into bf16-hi fragment planes ----
    {
        bf16x8* __restrict__ zfw = (bf16x8*)sU;
        const int r = tid & 127;             // row
        const int h = tid >> 7;              // K half
        const int w = r >> 5, s = (r >> 4) & 1, li = r & 15;
        #pragma unroll
        for (int g = 0; g < 4; ++g) {
            bf16x8 hi;
            #pragma unroll
            for (int i = 0; i < 8; ++i) {
                const float fv = zb[((size_t)(32 * h + 8 * g + i) << 12) + r];
                hi[i] = (__bf16)fv;
            }
            const int slot = (g << 4) | li;
            zfw[(w * 4 + s * 2 + h) * 65 + slot] = hi;
        }
    }
    __syncthreads();

    // ---- phase 1: MFMA screen; wave w owns rows [32w,32w+32) x all 1024 codes ----
    const int lane = tid & 63, w = tid >> 6;
    const int g = lane >> 4, li = lane & 15;

    const bf16x8* __restrict__ zf = (const bf16x8*)sU;
    const bf16x8 zh00 = zf[(w * 4 + 0) * 65 + lane];
    const bf16x8 zh01 = zf[(w * 4 + 1) * 65 + lane];
    const bf16x8 zh10 = zf[(w * 4 + 2) * 65 + lane];
    const bf16x8 zh11 = zf[(w * 4 + 3) * 65 + lane];

    float K0[2][4], K1[2][4], K2[2][4];
    #pragma unroll
    for (int s = 0; s < 2; ++s)
        #pragma unroll
        for (int j = 0; j < 4; ++j) { K0[s][j] = FLT_BIG; K1[s][j] = FLT_BIG; K2[s][j] = FLT_BIG; }

    const bf16x8* __restrict__ pe1 = (const bf16x8*)e1 + lane;
    const bf16x8* __restrict__ pe2 = (const bf16x8*)e2 + lane;
    const f32x4 zero = {0.f, 0.f, 0.f, 0.f};

    // register double-buffer: A holds tile t, B holds tile t+1 (preloaded)
    bf16x8 A1a = pe1[0], A1b = pe1[64], A2a = pe2[0], A2b = pe2[64];
    int tb = li;

    for (int t = 0; t < 64; t += 2) {
        const int o1 = (t + 1) * 128;
        const int o2 = (t + 2) * 128;    // at t=62: one-tile overread into pad (harmless)
        bf16x8 B1a = pe1[o1], B1b = pe1[o1 + 64], B2a = pe2[o1], B2b = pe2[o1 + 64];
        TILE_COMPUTE(A1a, A1b, A2a, A2b, tb)
        A1a = pe1[o2]; A1b = pe1[o2 + 64]; A2a = pe2[o2]; A2b = pe2[o2 + 64];
        TILE_COMPUTE(B1a, B1b, B2a, B2b, tb + 16)
        tb += 32;
    }

    __syncthreads();   // frag planes dead; reuse sU as sKey

    float* __restrict__ sKey = (float*)sU;
    #pragma unroll
    for (int s = 0; s < 2; ++s) {
        #pragma unroll
        for (int j = 0; j < 4; ++j) {
            const int row = 32 * w + 16 * s + 4 * g + j;
            const int base = row * CSTRIDE + li * 3;
            sKey[base + 0] = K0[s][j];
            sKey[base + 1] = K1[s][j];
            sKey[base + 2] = K2[s][j];
        }
    }
    __syncthreads();

    // ---- phase 2: exact numpy-semantics rescue, one thread per row ----
    if (tid < RPB) {
        const int r = tid;
        const int n = n0 + r;

        float gmin = FLT_BIG;
        #pragma unroll
        for (int s2 = 0; s2 < 48; ++s2) gmin = fminf(gmin, sKey[r * CSTRIDE + s2]);
        const float thr = gmin + DELTA;

        float zrow[CDIM];
        const float* __restrict__ zp = zb + r;
        #pragma unroll
        for (int c = 0; c < CDIM; ++c) zrow[c] = zp[(size_t)c << 12];  // coalesced
        const float A = pairwise_sq64(zrow);

        float bd = FLT_BIG;
        int bk = 1 << 30;
        for (int s2 = 0; s2 < 48; ++s2) {
            const float kv = sKey[r * CSTRIDE + s2];
            if (kv <= thr) {
                const int k = __float_as_int(kv) & 0x3FF;
                const float4* __restrict__ ek = (const float4*)(cb + (size_t)k * CDIM);
                float m = 0.f;
                #pragma unroll
                for (int q = 0; q < 16; ++q) {      // BLAS order: sequential in c
                    float4 e = ek[q];
                    m = __fmaf_rn(zrow[4 * q + 0], e.x, m);
                    m = __fmaf_rn(zrow[4 * q + 1], e.y, m);
                    m = __fmaf_rn(zrow[4 * q + 2], e.z, m);
                    m = __fmaf_rn(zrow[4 * q + 3], e.w, m);
                }
                const float d = __fsub_rn(__fadd_rn(A, sB[k]), __fadd_rn(m, m));
                if (d < bd || (d == bd && k < bk)) { bd = d; bk = k; }
            }
        }

        idx_out[n] = (float)bk;

        const float4* __restrict__ cq = (const float4*)(cb + (size_t)bk * CDIM);
        float* __restrict__ zo = zq_out + ((size_t)b << 18) + hw0 + r;
        float lsum = 0.f;
        #pragma unroll
        for (int q = 0; q < 16; ++q) {
            float4 qv = cq[q];
            zo[(size_t)(4 * q + 0) << 12] = qv.x;
            zo[(size_t)(4 * q + 1) << 12] = qv.y;
            zo[(size_t)(4 * q + 2) << 12] = qv.z;
            zo[(size_t)(4 * q + 3) << 12] = qv.w;
            lsum = fmaf(qv.x - zrow[4 * q + 0], qv.x - zrow[4 * q + 0], lsum);
            lsum = fmaf(qv.y - zrow[4 * q + 1], qv.y - zrow[4 * q + 1], lsum);
            lsum = fmaf(qv.z - zrow[4 * q + 2], qv.z - zrow[4 * q + 2], lsum);
            lsum = fmaf(qv.w - zrow[4 * q + 3], qv.w - zrow[4 * q + 3], lsum);
        }

        double ls = (double)lsum;
        for (int off = 32; off > 0; off >>= 1) ls += __shfl_down(ls, off, 64);
        if ((tid & 63) == 0) sP2[tid >> 6] = ls;
    }
    __syncthreads();
    if (tid == 0) part[blockIdx.x] = sP2[0] + sP2[1];
}

__global__ void vq_finalize(const double* __restrict__ part, float* __restrict__ loss_out) {
    __shared__ double s[16];
    const int tid = threadIdx.x;       // 1024 threads, one block
    double v = part[tid];
    for (int off = 32; off > 0; off >>= 1) v += __shfl_down(v, off, 64);
    if ((tid & 63) == 0) s[tid >> 6] = v;
    __syncthreads();
    if (tid == 0) {
        double t = 0.0;
        #pragma unroll
        for (int i = 0; i < 16; ++i) t += s[i];
        // loss = codebook_loss + 0.25*commitment = 1.25 * mean((z_q - z)^2)
        *loss_out = (float)(1.25 * t / (double)ZQ_ELEMS);
    }
}

extern "C" void kernel_launch(void* const* d_in, const int* in_sizes, int n_in,
                              void* d_out, int out_size, void* d_ws, size_t ws_size,
                              hipStream_t stream) {
    const float* z  = (const float*)d_in[0];
    const float* cb = (const float*)d_in[1];
    float* out  = (float*)d_out;
    float* zq   = out;                       // 8388608
    float* loss = out + ZQ_ELEMS;            // 1
    float* idx  = out + ZQ_ELEMS + 1;        // 131072
    char* ws = (char*)d_ws;
    double* part = (double*)ws;              // 1024 doubles
    float* Bsq   = (float*)(ws + WS_BSQ_OFF);
    __bf16* e1   = (__bf16*)(ws + WS_E1_OFF);
    __bf16* e2   = (__bf16*)(ws + WS_E2_OFF);

    vq_prep<<<4, 256, 0, stream>>>(cb, Bsq, e1, e2);
    vq_main<<<NBLK, 256, 0, stream>>>(z, cb, Bsq, e1, e2, zq, idx, part);
    vq_finalize<<<1, 1024, 0, stream>>>(part, loss);
}

// Round 15
// 78.544 us; speedup vs baseline: 2.9082x; 1.1486x over previous
//
#include <hip/hip_runtime.h>

#define CDIM 64
#define KCODES 1024
#define ZQ_ELEMS (32 * 64 * 64 * 64)  // 8388608
#define NROWS 131072
#define FLT_BIG 3.402823466e38f
#define RPB 128                       // rows per block
#define NBLK (NROWS / RPB)            // 1024
#define CSTRIDE 49                    // sKey row stride (floats); 48 slots used
#define DELTA 5e-4f                   // screen slack; err bound ~2e-4 (z_lo+e_lo dropped)

// ws layout: [0,8KB) part | [16KB,20KB) Bsq | [32KB,+128KB) e1 | +2KB overread pad after
#define WS_BSQ_OFF 16384
#define WS_E1_OFF  32768

typedef __bf16 bf16x8 __attribute__((ext_vector_type(8)));
typedef float  f32x4  __attribute__((ext_vector_type(4)));

// numpy-exact pairwise sum of squares (8 accumulators, numpy pairwise order)
__device__ __forceinline__ float pairwise_sq64(const float* v) {
    float r[8];
    #pragma unroll
    for (int j = 0; j < 8; ++j) r[j] = __fmul_rn(v[j], v[j]);
    #pragma unroll
    for (int m = 1; m < 8; ++m) {
        #pragma unroll
        for (int j = 0; j < 8; ++j)
            r[j] = __fadd_rn(r[j], __fmul_rn(v[8 * m + j], v[8 * m + j]));
    }
    return __fadd_rn(__fadd_rn(__fadd_rn(r[0], r[1]), __fadd_rn(r[2], r[3])),
                     __fadd_rn(__fadd_rn(r[4], r[5]), __fadd_rn(r[6], r[7])));
}

// ---------------- prep: exact code norms + bf16 codebook, B-fragment layout ----
__global__ __launch_bounds__(256) void vq_prep(const float* __restrict__ cb,
                                               float* __restrict__ Bsq,
                                               __bf16* __restrict__ e1) {
    const int k = blockIdx.x * 256 + threadIdx.x;   // 4 blocks -> 1024 codes
    const float* __restrict__ ck = cb + k * CDIM;
    float v[CDIM];
    #pragma unroll
    for (int q = 0; q < 16; ++q) {
        float4 t = ((const float4*)ck)[q];
        v[4 * q + 0] = t.x; v[4 * q + 1] = t.y; v[4 * q + 2] = t.z; v[4 * q + 3] = t.w;
    }
    Bsq[k] = pairwise_sq64(v);

    const int t = k >> 4, kin = k & 15;
    bf16x8* F1 = (bf16x8*)e1;
    #pragma unroll
    for (int ks = 0; ks < 2; ++ks) {
        #pragma unroll
        for (int g = 0; g < 4; ++g) {
            bf16x8 a;
            #pragma unroll
            for (int i = 0; i < 8; ++i) a[i] = (__bf16)v[ks * 32 + 8 * g + i];
            F1[(t * 2 + ks) * 64 + ((g << 4) | kin)] = a;
        }
    }
}

// branchless sorted-3 insert: fmaf + pack + min + 2*med3
#define INS(s, j, accv, Bv, code0) \
    { \
        const float vv = __fmaf_rn(-2.f, (accv), (Bv)); \
        const float kk = __int_as_float((__float_as_int(vv) & 0xFFFFFC00) | (code0)); \
        const float o0 = K0[s][j], o1 = K1[s][j], o2 = K2[s][j]; \
        K0[s][j] = fminf(o0, kk); \
        K1[s][j] = __builtin_amdgcn_fmed3f(o0, o1, kk); \
        K2[s][j] = __builtin_amdgcn_fmed3f(o1, o2, kk); \
    }

// one tile: 4 MFMA (2 per row-set, chained) + 8 inserts
#define TILE_COMPUTE(Ea, Eb, code0) \
    { \
        const float Bv = sB[code0]; \
        f32x4 a0 = __builtin_amdgcn_mfma_f32_16x16x32_bf16(zh00, Ea, zero, 0, 0, 0); \
        a0       = __builtin_amdgcn_mfma_f32_16x16x32_bf16(zh01, Eb, a0, 0, 0, 0); \
        f32x4 a1 = __builtin_amdgcn_mfma_f32_16x16x32_bf16(zh10, Ea, zero, 0, 0, 0); \
        a1       = __builtin_amdgcn_mfma_f32_16x16x32_bf16(zh11, Eb, a1, 0, 0, 0); \
        INS(0, 0, a0[0], Bv, code0) INS(0, 1, a0[1], Bv, code0) \
        INS(0, 2, a0[2], Bv, code0) INS(0, 3, a0[3], Bv, code0) \
        INS(1, 0, a1[0], Bv, code0) INS(1, 1, a1[1], Bv, code0) \
        INS(1, 2, a1[2], Bv, code0) INS(1, 3, a1[3], Bv, code0) \
    }

// ---------------- main: MFMA screen (e-hi only, reg-dbuf) + exact rescue ----------------
__global__ __launch_bounds__(256, 4) void vq_main(const float* __restrict__ z,
                                                  const float* __restrict__ cb,
                                                  const float* __restrict__ Bsq,
                                                  const __bf16* __restrict__ e1,
                                                  float* __restrict__ zq_out,
                                                  float* __restrict__ idx_out,
                                                  double* __restrict__ part) {
    // union: [phase 0/1] 16 frag-planes x 65 slots x 16B = 16640 B
    //        [phase 2]   sKey: 128 rows x 49 floats = 25088 B
    __shared__ __align__(16) unsigned char sU[25152];
    __shared__ float  sB[KCODES];
    __shared__ double sP2[2];

    const int tid = threadIdx.x;
    const int n0 = blockIdx.x * RPB;
    const int b = n0 >> 12;
    const int hw0 = n0 & 4095;
    const float* __restrict__ zb = z + ((size_t)b << 18) + hw0;

    for (int k = tid; k < KCODES; k += 256) sB[k] = Bsq[k];

    // ---- phase 0: cooperative z staging into bf16-hi fragment planes ----
    {
        bf16x8* __restrict__ zfw = (bf16x8*)sU;
        const int r = tid & 127;             // row
        const int h = tid >> 7;              // K half
        const int w = r >> 5, s = (r >> 4) & 1, li = r & 15;
        #pragma unroll
        for (int g = 0; g < 4; ++g) {
            bf16x8 hi;
            #pragma unroll
            for (int i = 0; i < 8; ++i) {
                const float fv = zb[((size_t)(32 * h + 8 * g + i) << 12) + r];
                hi[i] = (__bf16)fv;
            }
            const int slot = (g << 4) | li;
            zfw[(w * 4 + s * 2 + h) * 65 + slot] = hi;
        }
    }
    __syncthreads();

    // ---- phase 1: MFMA screen; wave w owns rows [32w,32w+32) x all 1024 codes ----
    const int lane = tid & 63, w = tid >> 6;
    const int g = lane >> 4, li = lane & 15;

    const bf16x8* __restrict__ zf = (const bf16x8*)sU;
    const bf16x8 zh00 = zf[(w * 4 + 0) * 65 + lane];
    const bf16x8 zh01 = zf[(w * 4 + 1) * 65 + lane];
    const bf16x8 zh10 = zf[(w * 4 + 2) * 65 + lane];
    const bf16x8 zh11 = zf[(w * 4 + 3) * 65 + lane];

    float K0[2][4], K1[2][4], K2[2][4];
    #pragma unroll
    for (int s = 0; s < 2; ++s)
        #pragma unroll
        for (int j = 0; j < 4; ++j) { K0[s][j] = FLT_BIG; K1[s][j] = FLT_BIG; K2[s][j] = FLT_BIG; }

    const bf16x8* __restrict__ pe1 = (const bf16x8*)e1 + lane;
    const f32x4 zero = {0.f, 0.f, 0.f, 0.f};

    // register double-buffer over e1 tiles (8 bf16x8 total live)
    bf16x8 A1a = pe1[0], A1b = pe1[64];
    int tb = li;

    for (int t = 0; t < 64; t += 2) {
        const int o1 = (t + 1) * 128;
        const int o2 = (t + 2) * 128;    // at t=62: one-tile overread into pad (harmless)
        bf16x8 B1a = pe1[o1], B1b = pe1[o1 + 64];
        TILE_COMPUTE(A1a, A1b, tb)
        A1a = pe1[o2]; A1b = pe1[o2 + 64];
        TILE_COMPUTE(B1a, B1b, tb + 16)
        tb += 32;
    }

    __syncthreads();   // frag planes dead; reuse sU as sKey

    float* __restrict__ sKey = (float*)sU;
    #pragma unroll
    for (int s = 0; s < 2; ++s) {
        #pragma unroll
        for (int j = 0; j < 4; ++j) {
            const int row = 32 * w + 16 * s + 4 * g + j;
            const int base = row * CSTRIDE + li * 3;
            sKey[base + 0] = K0[s][j];
            sKey[base + 1] = K1[s][j];
            sKey[base + 2] = K2[s][j];
        }
    }
    __syncthreads();

    // ---- phase 2: exact numpy-semantics rescue, one thread per row ----
    if (tid < RPB) {
        const int r = tid;
        const int n = n0 + r;

        float gmin = FLT_BIG;
        #pragma unroll
        for (int s2 = 0; s2 < 48; ++s2) gmin = fminf(gmin, sKey[r * CSTRIDE + s2]);
        const float thr = gmin + DELTA;

        float zrow[CDIM];
        const float* __restrict__ zp = zb + r;
        #pragma unroll
        for (int c = 0; c < CDIM; ++c) zrow[c] = zp[(size_t)c << 12];  // coalesced
        const float A = pairwise_sq64(zrow);

        float bd = FLT_BIG;
        int bk = 1 << 30;
        for (int s2 = 0; s2 < 48; ++s2) {
            const float kv = sKey[r * CSTRIDE + s2];
            if (kv <= thr) {
                const int k = __float_as_int(kv) & 0x3FF;
                const float4* __restrict__ ek = (const float4*)(cb + (size_t)k * CDIM);
                float m = 0.f;
                #pragma unroll
                for (int q = 0; q < 16; ++q) {      // BLAS order: sequential in c
                    float4 e = ek[q];
                    m = __fmaf_rn(zrow[4 * q + 0], e.x, m);
                    m = __fmaf_rn(zrow[4 * q + 1], e.y, m);
                    m = __fmaf_rn(zrow[4 * q + 2], e.z, m);
                    m = __fmaf_rn(zrow[4 * q + 3], e.w, m);
                }
                const float d = __fsub_rn(__fadd_rn(A, sB[k]), __fadd_rn(m, m));
                if (d < bd || (d == bd && k < bk)) { bd = d; bk = k; }
            }
        }

        idx_out[n] = (float)bk;

        const float4* __restrict__ cq = (const float4*)(cb + (size_t)bk * CDIM);
        float* __restrict__ zo = zq_out + ((size_t)b << 18) + hw0 + r;
        float lsum = 0.f;
        #pragma unroll
        for (int q = 0; q < 16; ++q) {
            float4 qv = cq[q];
            zo[(size_t)(4 * q + 0) << 12] = qv.x;
            zo[(size_t)(4 * q + 1) << 12] = qv.y;
            zo[(size_t)(4 * q + 2) << 12] = qv.z;
            zo[(size_t)(4 * q + 3) << 12] = qv.w;
            lsum = fmaf(qv.x - zrow[4 * q + 0], qv.x - zrow[4 * q + 0], lsum);
            lsum = fmaf(qv.y - zrow[4 * q + 1], qv.y - zrow[4 * q + 1], lsum);
            lsum = fmaf(qv.z - zrow[4 * q + 2], qv.z - zrow[4 * q + 2], lsum);
            lsum = fmaf(qv.w - zrow[4 * q + 3], qv.w - zrow[4 * q + 3], lsum);
        }

        double ls = (double)lsum;
        for (int off = 32; off > 0; off >>= 1) ls += __shfl_down(ls, off, 64);
        if ((tid & 63) == 0) sP2[tid >> 6] = ls;
    }
    __syncthreads();
    if (tid == 0) part[blockIdx.x] = sP2[0] + sP2[1];
}

__global__ void vq_finalize(const double* __restrict__ part, float* __restrict__ loss_out) {
    __shared__ double s[16];
    const int tid = threadIdx.x;       // 1024 threads, one block
    double v = part[tid];
    for (int off = 32; off > 0; off >>= 1) v += __shfl_down(v, off, 64);
    if ((tid & 63) == 0) s[tid >> 6] = v;
    __syncthreads();
    if (tid == 0) {
        double t = 0.0;
        #pragma unroll
        for (int i = 0; i < 16; ++i) t += s[i];
        // loss = codebook_loss + 0.25*commitment = 1.25 * mean((z_q - z)^2)
        *loss_out = (float)(1.25 * t / (double)ZQ_ELEMS);
    }
}

extern "C" void kernel_launch(void* const* d_in, const int* in_sizes, int n_in,
                              void* d_out, int out_size, void* d_ws, size_t ws_size,
                              hipStream_t stream) {
    const float* z  = (const float*)d_in[0];
    const float* cb = (const float*)d_in[1];
    float* out  = (float*)d_out;
    float* zq   = out;                       // 8388608
    float* loss = out + ZQ_ELEMS;            // 1
    float* idx  = out + ZQ_ELEMS + 1;        // 131072
    char* ws = (char*)d_ws;
    double* part = (double*)ws;              // 1024 doubles
    float* Bsq   = (float*)(ws + WS_BSQ_OFF);
    __bf16* e1   = (__bf16*)(ws + WS_E1_OFF);

    vq_prep<<<4, 256, 0, stream>>>(cb, Bsq, e1);
    vq_main<<<NBLK, 256, 0, stream>>>(z, cb, Bsq, e1, zq, idx, part);
    vq_finalize<<<1, 1024, 0, stream>>>(part, loss);
}